// Round 1
// baseline (122.795 us; speedup 1.0000x reference)
//
#include <hip/hip_runtime.h>

#define NUM_NODES  1048576
#define NUM_FEAT   128
#define HIDDEN     64
#define NUM_GRAPHS 4096
#define OUT_DIM    5

// One block per graph. batch is sorted -> binary search segment bounds,
// accumulate column sums with float4 loads, LDS-reduce, then fused MLP head.
__global__ __launch_bounds__(256) void gcn_fused_kernel(
    const float* __restrict__ x,
    const int*   __restrict__ batch,
    const float* __restrict__ W1, const float* __restrict__ b1,
    const float* __restrict__ W2, const float* __restrict__ b2,
    const float* __restrict__ W3, const float* __restrict__ b3,
    float* __restrict__ out)
{
    const int g = blockIdx.x;
    const int t = threadIdx.x;

    // lower_bound(batch, g) and lower_bound(batch, g+1); uniform across block,
    // per-wave same-address loads broadcast.
    int lo = 0, hi = NUM_NODES;
    while (lo < hi) { int mid = (lo + hi) >> 1; if (batch[mid] < g) lo = mid + 1; else hi = mid; }
    const int start = lo;
    hi = NUM_NODES;
    while (lo < hi) { int mid = (lo + hi) >> 1; if (batch[mid] < g + 1) lo = mid + 1; else hi = mid; }
    const int end = lo;
    const int count = end - start;

    // 256 threads: 32 column-groups (float4) x 8 row-phases.
    const int cg = t & 31;   // column group: floats [4*cg, 4*cg+3]
    const int ro = t >> 5;   // row offset 0..7

    float4 acc = make_float4(0.f, 0.f, 0.f, 0.f);
    for (int r = start + ro; r < end; r += 8) {
        const float4 v = *reinterpret_cast<const float4*>(x + (size_t)r * NUM_FEAT + cg * 4);
        acc.x += v.x; acc.y += v.y; acc.z += v.z; acc.w += v.w;
    }

    __shared__ float4 part[256];
    __shared__ float  pooled[NUM_FEAT];
    __shared__ float  h1[HIDDEN];
    __shared__ float  h2[HIDDEN];

    part[t] = acc;
    __syncthreads();

    if (t < 32) {
        float4 s = part[t];
        #pragma unroll
        for (int o = 1; o < 8; ++o) {
            const float4 p = part[t + o * 32];
            s.x += p.x; s.y += p.y; s.z += p.z; s.w += p.w;
        }
        const float inv = (count > 0) ? (1.0f / (float)count) : 0.0f;
        pooled[t * 4 + 0] = s.x * inv;
        pooled[t * 4 + 1] = s.y * inv;
        pooled[t * 4 + 2] = s.z * inv;
        pooled[t * 4 + 3] = s.w * inv;
    }
    __syncthreads();

    // h1 = relu(pooled @ W1 + b1); W1 is [128][64] row-major -> coalesced over t
    if (t < HIDDEN) {
        float s = b1[t];
        #pragma unroll 8
        for (int k = 0; k < NUM_FEAT; ++k) s = fmaf(pooled[k], W1[k * HIDDEN + t], s);
        h1[t] = fmaxf(s, 0.0f);
    }
    __syncthreads();

    // h2 = relu(h1 @ W2 + b2); W2 is [64][64]
    if (t < HIDDEN) {
        float s = b2[t];
        #pragma unroll 8
        for (int k = 0; k < HIDDEN; ++k) s = fmaf(h1[k], W2[k * HIDDEN + t], s);
        h2[t] = fmaxf(s, 0.0f);
    }
    __syncthreads();

    // out = h2 @ W3 + b3; W3 is [64][5]
    if (t < OUT_DIM) {
        float s = b3[t];
        #pragma unroll 8
        for (int k = 0; k < HIDDEN; ++k) s = fmaf(h2[k], W3[k * OUT_DIM + t], s);
        out[g * OUT_DIM + t] = s;
    }
}

extern "C" void kernel_launch(void* const* d_in, const int* in_sizes, int n_in,
                              void* d_out, int out_size, void* d_ws, size_t ws_size,
                              hipStream_t stream) {
    const float* x     = (const float*)d_in[0];
    const int*   batch = (const int*)d_in[1];
    const float* W1    = (const float*)d_in[2];
    const float* b1    = (const float*)d_in[3];
    const float* W2    = (const float*)d_in[4];
    const float* b2    = (const float*)d_in[5];
    const float* W3    = (const float*)d_in[6];
    const float* b3    = (const float*)d_in[7];
    float* out = (float*)d_out;

    gcn_fused_kernel<<<NUM_GRAPHS, 256, 0, stream>>>(x, batch, W1, b1, W2, b2, W3, b3, out);
}

// Round 2
// 114.717 us; speedup vs baseline: 1.0704x; 1.0704x over previous
//
#include <hip/hip_runtime.h>

#define NUM_NODES  1048576
#define NUM_FEAT   128
#define HIDDEN     64
#define NUM_GRAPHS 4096
#define OUT_DIM    5

// Kernel A: seg[g] = lower_bound(batch, g) for g in [0, NUM_GRAPHS].
// 4097 independent binary searches, fully parallel (latency-overlapped).
__global__ __launch_bounds__(256) void seg_bounds_kernel(
    const int* __restrict__ batch, int* __restrict__ seg)
{
    const int g = blockIdx.x * blockDim.x + threadIdx.x;
    if (g > NUM_GRAPHS) return;
    int lo = 0, hi = NUM_NODES;
    while (lo < hi) { int mid = (lo + hi) >> 1; if (batch[mid] < g) lo = mid + 1; else hi = mid; }
    seg[g] = lo;
}

// Kernel B: one 128-thread block per graph. 16 blocks/CU x 2 waves = 32 waves
// (full occupancy, single residency generation). Stream segment rows with
// float4 loads, LDS-reduce, fused MLP head.
__global__ __launch_bounds__(128, 8) void gcn_fused_kernel(
    const float* __restrict__ x,
    const int*   __restrict__ seg,
    const float* __restrict__ W1, const float* __restrict__ b1,
    const float* __restrict__ W2, const float* __restrict__ b2,
    const float* __restrict__ W3, const float* __restrict__ b3,
    float* __restrict__ out)
{
    const int g = blockIdx.x;
    const int t = threadIdx.x;

    const int start = seg[g];
    const int end   = seg[g + 1];
    const int count = end - start;

    // 128 threads: 32 column-groups (float4) x 4 row-phases.
    const int cg = t & 31;   // column group: floats [4*cg, 4*cg+3]
    const int ro = t >> 5;   // row offset 0..3

    float4 acc = make_float4(0.f, 0.f, 0.f, 0.f);
    for (int r = start + ro; r < end; r += 4) {
        const float4 v = *reinterpret_cast<const float4*>(x + (size_t)r * NUM_FEAT + cg * 4);
        acc.x += v.x; acc.y += v.y; acc.z += v.z; acc.w += v.w;
    }

    __shared__ float4 part[128];
    __shared__ float  pooled[NUM_FEAT];
    __shared__ float  h1[HIDDEN];
    __shared__ float  h2[HIDDEN];

    part[t] = acc;
    __syncthreads();

    if (t < 32) {
        float4 s = part[t];
        #pragma unroll
        for (int o = 1; o < 4; ++o) {
            const float4 p = part[t + o * 32];
            s.x += p.x; s.y += p.y; s.z += p.z; s.w += p.w;
        }
        const float inv = (count > 0) ? (1.0f / (float)count) : 0.0f;
        pooled[t * 4 + 0] = s.x * inv;
        pooled[t * 4 + 1] = s.y * inv;
        pooled[t * 4 + 2] = s.z * inv;
        pooled[t * 4 + 3] = s.w * inv;
    }
    __syncthreads();

    // h1 = relu(pooled @ W1 + b1); W1 [128][64] row-major -> coalesced over t
    if (t < HIDDEN) {
        float s = b1[t];
        #pragma unroll 8
        for (int k = 0; k < NUM_FEAT; ++k) s = fmaf(pooled[k], W1[k * HIDDEN + t], s);
        h1[t] = fmaxf(s, 0.0f);
    }
    __syncthreads();

    // h2 = relu(h1 @ W2 + b2); W2 [64][64]
    if (t < HIDDEN) {
        float s = b2[t];
        #pragma unroll 8
        for (int k = 0; k < HIDDEN; ++k) s = fmaf(h1[k], W2[k * HIDDEN + t], s);
        h2[t] = fmaxf(s, 0.0f);
    }
    __syncthreads();

    // out = h2 @ W3 + b3; W3 [64][5]
    if (t < OUT_DIM) {
        float s = b3[t];
        #pragma unroll 8
        for (int k = 0; k < HIDDEN; ++k) s = fmaf(h2[k], W3[k * OUT_DIM + t], s);
        out[g * OUT_DIM + t] = s;
    }
}

extern "C" void kernel_launch(void* const* d_in, const int* in_sizes, int n_in,
                              void* d_out, int out_size, void* d_ws, size_t ws_size,
                              hipStream_t stream) {
    const float* x     = (const float*)d_in[0];
    const int*   batch = (const int*)d_in[1];
    const float* W1    = (const float*)d_in[2];
    const float* b1    = (const float*)d_in[3];
    const float* W2    = (const float*)d_in[4];
    const float* b2    = (const float*)d_in[5];
    const float* W3    = (const float*)d_in[6];
    const float* b3    = (const float*)d_in[7];
    float* out = (float*)d_out;

    int* seg = (int*)d_ws;  // NUM_GRAPHS + 1 ints

    seg_bounds_kernel<<<(NUM_GRAPHS + 1 + 255) / 256, 256, 0, stream>>>(batch, seg);
    gcn_fused_kernel<<<NUM_GRAPHS, 128, 0, stream>>>(x, seg, W1, b1, W2, b2, W3, b3, out);
}

// Round 3
// 99.090 us; speedup vs baseline: 1.2392x; 1.1577x over previous
//
#include <hip/hip_runtime.h>

#define NUM_NODES  1048576
#define NUM_FEAT   128
#define HIDDEN     64
#define NUM_GRAPHS 4096
#define OUT_DIM    5

typedef float f32x4 __attribute__((ext_vector_type(4)));

// Kernel A: streaming boundary scan. seg[g] = lower_bound(batch, g).
// Each thread i reads batch[i], batch[i-1] (coalesced, neighbor line in L1);
// at a transition prev < g <= batch[i], thread i owns seg[g] = i.
__global__ __launch_bounds__(256) void seg_scan_kernel(
    const int* __restrict__ batch, int* __restrict__ seg)
{
    const int i = blockIdx.x * blockDim.x + threadIdx.x;
    if (i >= NUM_NODES) return;
    const int b = batch[i];
    const int prev = (i == 0) ? -1 : batch[i - 1];
    for (int g = prev + 1; g <= b; ++g) seg[g] = i;
    if (i == NUM_NODES - 1) {
        for (int g = b + 1; g <= NUM_GRAPHS; ++g) seg[g] = NUM_NODES;
    }
}

// Kernel B: one 128-thread block per graph (16 blocks/CU = 32 waves/CU, single
// residency generation). Non-temporal dual-accumulator streaming of the
// segment, LDS reduce, fused MLP head.
__global__ __launch_bounds__(128, 8) void gcn_fused_kernel(
    const float* __restrict__ x,
    const int*   __restrict__ seg,
    const float* __restrict__ W1, const float* __restrict__ b1,
    const float* __restrict__ W2, const float* __restrict__ b2,
    const float* __restrict__ W3, const float* __restrict__ b3,
    float* __restrict__ out)
{
    const int g = blockIdx.x;
    const int t = threadIdx.x;

    const int start = seg[g];
    const int end   = seg[g + 1];
    const int count = end - start;

    // 128 threads: 32 column-groups (float4) x 4 row-phases.
    const int cg = t & 31;   // floats [4*cg, 4*cg+3]
    const int ro = t >> 5;   // row offset 0..3

    // rows handled by this thread: start+ro, start+ro+4, ...
    int iters = count - ro + 3;
    iters = (iters > 0) ? (iters >> 2) : 0;

    const f32x4* p = reinterpret_cast<const f32x4*>(
        x + (size_t)(start + ro) * NUM_FEAT) + cg;
    const int step = NUM_FEAT;  // f32x4 elements per 4 rows: 4*128/4 = 128

    f32x4 acc0 = (f32x4)0.0f, acc1 = (f32x4)0.0f;
    int i = 0;
    for (; i + 2 <= iters; i += 2) {
        const f32x4 v0 = __builtin_nontemporal_load(p);
        const f32x4 v1 = __builtin_nontemporal_load(p + step);
        acc0 += v0;
        acc1 += v1;
        p += 2 * step;
    }
    if (i < iters) {
        acc0 += __builtin_nontemporal_load(p);
    }
    f32x4 acc = acc0 + acc1;

    __shared__ f32x4 part[128];
    __shared__ float pooled[NUM_FEAT];
    __shared__ float h1[HIDDEN];
    __shared__ float h2[HIDDEN];

    part[t] = acc;
    __syncthreads();

    if (t < 32) {
        f32x4 s = part[t] + part[t + 32] + part[t + 64] + part[t + 96];
        const float inv = (count > 0) ? (1.0f / (float)count) : 0.0f;
        pooled[t * 4 + 0] = s.x * inv;
        pooled[t * 4 + 1] = s.y * inv;
        pooled[t * 4 + 2] = s.z * inv;
        pooled[t * 4 + 3] = s.w * inv;
    }
    __syncthreads();

    // h1 = relu(pooled @ W1 + b1); W1 [128][64] row-major -> coalesced over t
    if (t < HIDDEN) {
        float s = b1[t];
        #pragma unroll 8
        for (int k = 0; k < NUM_FEAT; ++k) s = fmaf(pooled[k], W1[k * HIDDEN + t], s);
        h1[t] = fmaxf(s, 0.0f);
    }
    __syncthreads();

    // h2 = relu(h1 @ W2 + b2); W2 [64][64]
    if (t < HIDDEN) {
        float s = b2[t];
        #pragma unroll 8
        for (int k = 0; k < HIDDEN; ++k) s = fmaf(h1[k], W2[k * HIDDEN + t], s);
        h2[t] = fmaxf(s, 0.0f);
    }
    __syncthreads();

    // out = h2 @ W3 + b3; W3 [64][5]
    if (t < OUT_DIM) {
        float s = b3[t];
        #pragma unroll 8
        for (int k = 0; k < HIDDEN; ++k) s = fmaf(h2[k], W3[k * OUT_DIM + t], s);
        out[g * OUT_DIM + t] = s;
    }
}

extern "C" void kernel_launch(void* const* d_in, const int* in_sizes, int n_in,
                              void* d_out, int out_size, void* d_ws, size_t ws_size,
                              hipStream_t stream) {
    const float* x     = (const float*)d_in[0];
    const int*   batch = (const int*)d_in[1];
    const float* W1    = (const float*)d_in[2];
    const float* b1    = (const float*)d_in[3];
    const float* W2    = (const float*)d_in[4];
    const float* b2    = (const float*)d_in[5];
    const float* W3    = (const float*)d_in[6];
    const float* b3    = (const float*)d_in[7];
    float* out = (float*)d_out;

    int* seg = (int*)d_ws;  // NUM_GRAPHS + 1 ints

    seg_scan_kernel<<<NUM_NODES / 256, 256, 0, stream>>>(batch, seg);
    gcn_fused_kernel<<<NUM_GRAPHS, 128, 0, stream>>>(x, seg, W1, b1, W2, b2, W3, b3, out);
}